// Round 12
// baseline (426.383 us; speedup 1.0000x reference)
//
#include <hip/hip_runtime.h>

// ---------------- problem constants ----------------
#define VOCAB 18
#define EMB   200
#define HID   200
#define G4    800           // 4*HID
#define SEQ   128
#define BATCH 2048
#define MB    8             // batch rows per block
#define NT    56            // N tiles: 50 gate (j-blocked) + 2 logit + 4 zero
#define KS    7             // K steps of 32 -> 224 padded K
                            // k<200: W_hh | k=200: logit bias | k=201+v: tbl[v]
#define TPB   256           // 4 waves -> 1 wave/SIMD -> 512-reg budget
#define TPW   14            // tiles per wave (56/4) -> 392 pinned AGPRs
#define SV    (SEQ*VOCAB)   // 2304
#define LOGITS_N ((size_t)BATCH*SEQ*VOCAB)

typedef short s16x8 __attribute__((ext_vector_type(8)));
typedef float f32x4 __attribute__((ext_vector_type(4)));

__device__ __forceinline__ unsigned short f2bf(float f) {
  unsigned int u = __float_as_uint(f);
  u += 0x7FFFu + ((u >> 16) & 1u);            // RNE; no NaNs in this problem
  return (unsigned short)(u >> 16);
}
__device__ __forceinline__ float sigm(float x) {
  float e = __builtin_amdgcn_exp2f(x * 1.4426950408889634f);
  return e * __builtin_amdgcn_rcpf(e + 1.0f);
}
__device__ __forceinline__ float tanhq(float x) {
  float e = __builtin_amdgcn_exp2f(x * 2.8853900817779268f); // exp2(2x*log2e)
  return 1.0f - 2.0f * __builtin_amdgcn_rcpf(e + 1.0f);
}
// quad_perm DPP: xor1 = [1,0,3,2] = 0xB1 ; xor2 = [2,3,0,1] = 0x4E
__device__ __forceinline__ float dpp_x1(float v) {
  return __uint_as_float((unsigned)__builtin_amdgcn_mov_dpp(
      (int)__float_as_uint(v), 0xB1, 0xF, 0xF, true));
}
__device__ __forceinline__ float dpp_x2(float v) {
  return __uint_as_float((unsigned)__builtin_amdgcn_mov_dpp(
      (int)__float_as_uint(v), 0x4E, 0xF, 0xF, true));
}

// ---------------- prep 1: token table (gate-major cols, bf16 18x800) ------
__global__ void prep_tbl(const float* __restrict__ E, const float* __restrict__ W_ih,
                         const float* __restrict__ b_ih, const float* __restrict__ b_hh,
                         unsigned short* __restrict__ tbl) {
  int tid = blockIdx.x * 256 + threadIdx.x;
  if (tid >= VOCAB * G4) return;
  int v = tid / G4, col = tid % G4;
  float s = b_ih[col] + b_hh[col];
  if (v != 0) {
    const float* Er = E + v * EMB;
    const float* Wr = W_ih + col * EMB;
    for (int e = 0; e < EMB; ++e) s += Er[e] * Wr[e];
  }
  tbl[tid] = f2bf(s);
}

// ---------------- prep 2: pack Wp (j-blocked gate tiles) ----------------
// B-frag order: lane l elem i = B[32s+8*(l>>4)+i][tile n, c=(l&15)].
// Gate tiles n<50: c = jj*4+g -> gate g, hid j = 4n+jj; gate-major col = g*200+j.
// Logit tiles n=50,51: v = 16(n-50)+c.
__global__ void prep_wp(const float* __restrict__ W_hh, const float* __restrict__ W_out,
                        const float* __restrict__ b_out,
                        const unsigned short* __restrict__ tbl,
                        short* __restrict__ Wp) {
  int u = blockIdx.x * 256 + threadIdx.x;
  if (u >= NT * KS * 64) return;
  int n    = u / (KS * 64);
  int rem  = u % (KS * 64);
  int s_   = rem >> 6;
  int lane = rem & 63;
  int c    = lane & 15;
  int kb   = lane >> 4;
  s16x8 o;
  #pragma unroll
  for (int i = 0; i < 8; ++i) {
    int k = 32 * s_ + 8 * kb + i;
    short b = 0;
    if (n < 50) {
      int g = c & 3, j = 4 * n + (c >> 2);
      int colg = g * 200 + j;
      if (k < HID)                          b = (short)f2bf(W_hh[colg * HID + k]);
      else if (k >= 201 && k < 201 + VOCAB) b = (short)tbl[(k - 201) * G4 + colg];
    } else if (n < 52) {
      int v = 16 * (n - 50) + c;
      if (v < VOCAB) {
        if (k < HID)       b = (short)f2bf(W_out[v * HID + k]);
        else if (k == HID) b = (short)f2bf(b_out[v]);
      }
    }
    o[i] = b;
  }
  *(s16x8*)(Wp + (size_t)u * 8) = o;
}

// ---------------- main ----------------
// 4 waves (1/SIMD), 392 pinned weight AGPRs/wave. Per step: software-pipelined
// pairs — MFMA pair P+1 issued, then pair P's DPP-transpose + activations run
// as pure VALU in the matrix pipe's shadow (no LDS scratch, no lgkm waits).
__global__ __launch_bounds__(TPB) __attribute__((amdgpu_waves_per_eu(1, 1)))
void lstm_kernel(const int* __restrict__ x, const short* __restrict__ Wp,
                 float* __restrict__ out) {
  __shared__ unsigned short hA[KS * 64 * 8];   // h in A-frag layout bf16 (7.2KB)
  __shared__ int   xtok[MB * SEQ];             // 4KB
  __shared__ float logL[MB * SV];              // logits buffer (73.7KB)

  const int tid  = threadIdx.x;
  const int lane = tid & 63;
  const int w    = tid >> 6;                   // wave 0..3
  const int blk  = blockIdx.x;
  const int jw   = 56 * w;                     // wave's j base
  const int jj   = (lane >> 2) & 3;            // col-group within tile
  const int row  = 4 * ((lane >> 4) & 3) + (lane & 3); // valid for lanes<32
  const bool pb0 = lane & 1, pb1 = lane & 2;   // transpose select bits

  // h0 = 0; bf16 1.0 at bias row k=200 (elems 3200+8r)
  for (int i = tid; i < KS * 64 * 8; i += TPB)
    hA[i] = (i >= 3200 && i < 3264 && (i & 7) == 0) ? (unsigned short)0x3F80
                                                    : (unsigned short)0;
  for (int i = tid; i < MB * SEQ; i += TPB) xtok[i] = x[blk * (MB * SEQ) + i];

  // weight fragments: 14 tiles x 7 steps x 4 regs = 392 AGPRs, pinned once.
  s16x8 wf[TPW][KS];
  #pragma unroll
  for (int n = 0; n < TPW; ++n) {
    #pragma unroll
    for (int s = 0; s < KS; ++s) {
      wf[n][s] = *(const s16x8*)(Wp + ((((w * TPW + n) * KS) + s) * 64 + lane) * 8);
      asm volatile("" : "+a"(wf[n][s]));
    }
    asm volatile("" ::: "memory");
  }

  float cA[7] = {0,0,0,0,0,0,0}, cB[7] = {0,0,0,0,0,0,0};
  const f32x4 zz = {0.f, 0.f, 0.f, 0.f};
  __syncthreads();

#define MFMA_PAIR(nt, A, B) {                                                   \
    _Pragma("unroll")                                                           \
    for (int s = 0; s < KS; ++s) {                                              \
      A = __builtin_amdgcn_mfma_f32_16x16x32_bf16(aF[s], wf[nt][s],     A, 0,0,0); \
      B = __builtin_amdgcn_mfma_f32_16x16x32_bf16(aF[s], wf[(nt)+1][s], B, 0,0,0); \
    } }

// corrected 4x4 XOR butterfly: stage1 exchanges CROSS registers (0<->1, 2<->3)
// across lane^1, stage2 exchanges (0<->2, 1<->3) across lane^2.
// Result: lane p, reg g  =  original lane g, reg p  (within each quad).
#define TRANS4(v) {                                                             \
    float t0 = dpp_x1(v[0]), t1 = dpp_x1(v[1]), t2 = dpp_x1(v[2]), t3 = dpp_x1(v[3]); \
    v[0] = pb0 ? t1 : v[0];  v[1] = pb0 ? v[1] : t0;                            \
    v[2] = pb0 ? t3 : v[2];  v[3] = pb0 ? v[3] : t2;                            \
    t0 = dpp_x2(v[0]); t1 = dpp_x2(v[1]); t2 = dpp_x2(v[2]); t3 = dpp_x2(v[3]); \
    v[0] = pb1 ? t2 : v[0];  v[1] = pb1 ? t3 : v[1];                            \
    v[2] = pb1 ? v[2] : t0;  v[3] = pb1 ? v[3] : t1; }

#define EWONE(V, CC, J) {                                                       \
    float i_ = sigm(V[0]), f_ = sigm(V[1]), g_ = tanhq(V[2]), o_ = sigm(V[3]);  \
    float cn = f_ * (CC) + i_ * g_;                                             \
    float h  = o_ * tanhq(cn);                                                  \
    (CC) = cn;                                                                  \
    hA[(((J) >> 5) * 64 + 16 * (((J) >> 3) & 3) + row) * 8 + ((J) & 7)] = f2bf(h); \
    if (t == SEQ - 1) {                                                         \
      size_t bg = (size_t)blk * MB + row;                                       \
      out[LOGITS_N + bg * HID + (J)] = h;                                       \
      out[LOGITS_N + (size_t)BATCH * HID + bg * HID + (J)] = cn;                \
    } }

#define EW_PAIR(P, A, B) {                                                      \
    TRANS4(A); TRANS4(B);                                                       \
    if (lane < 32) {                                                            \
      int jA = jw + 8 * (P) + jj;                                               \
      EWONE(A, cA[P], jA);                                                      \
      EWONE(B, cB[P], jA + 4);                                                  \
    } }

#define LOGIT_STORE(A, B)                                                       \
    if (t > 0 && lane < 32) {                                                   \
      int qrow = (lane >> 4) * 4, c = lane & 15;                                \
      _Pragma("unroll")                                                         \
      for (int q = 0; q < 4; ++q) {                                             \
        logL[(qrow + q) * SV + (t - 1) * VOCAB + c] = A[q];                     \
        if (c < 2) logL[(qrow + q) * SV + (t - 1) * VOCAB + 16 + c] = B[q];     \
      } }

  #pragma unroll 1
  for (int t = 0; t < SEQ; ++t) {
    // ---- load A fragments; inject one-hot token row into aF[6] in-register ----
    s16x8 aF[KS];
    #pragma unroll
    for (int s = 0; s < KS; ++s) aF[s] = *(const s16x8*)&hA[(s * 64 + lane) * 8];
    {
      int vv = xtok[(lane & 7) * SEQ + t];
      int js = (lane & 8) ? 100 : (vv + 9 - 8 * (lane >> 4)); // elem for k=201+vv
      s16x8 a6 = aF[6];
      #pragma unroll
      for (int e = 0; e < 8; ++e)
        a6[e] = (e == js) ? (short)0x3F80 : a6[e];
      aF[6] = a6;
    }
    __syncthreads();   // all waves hold h_t before anyone stores h_{t+1}

    if (w < 3) {       // 7 gate pairs, 2-stage software pipeline
      f32x4 A0 = zz, B0 = zz, A1 = zz, B1 = zz;
      MFMA_PAIR(0, A0, B0);
      MFMA_PAIR(2, A1, B1);   EW_PAIR(0, A0, B0);
      A0 = zz; B0 = zz;
      MFMA_PAIR(4, A0, B0);   EW_PAIR(1, A1, B1);
      A1 = zz; B1 = zz;
      MFMA_PAIR(6, A1, B1);   EW_PAIR(2, A0, B0);
      A0 = zz; B0 = zz;
      MFMA_PAIR(8, A0, B0);   EW_PAIR(3, A1, B1);
      A1 = zz; B1 = zz;
      MFMA_PAIR(10, A1, B1);  EW_PAIR(4, A0, B0);
      A0 = zz; B0 = zz;
      MFMA_PAIR(12, A0, B0);  EW_PAIR(5, A1, B1);
      EW_PAIR(6, A0, B0);
    } else {           // 4 gate pairs + logit pair (wf[8], wf[9])
      f32x4 A0 = zz, B0 = zz, A1 = zz, B1 = zz;
      MFMA_PAIR(0, A0, B0);
      MFMA_PAIR(2, A1, B1);   EW_PAIR(0, A0, B0);
      A0 = zz; B0 = zz;
      MFMA_PAIR(4, A0, B0);   EW_PAIR(1, A1, B1);
      A1 = zz; B1 = zz;
      MFMA_PAIR(6, A1, B1);   EW_PAIR(2, A0, B0);
      A0 = zz; B0 = zz;
      MFMA_PAIR(8, A0, B0);   EW_PAIR(3, A1, B1);   // logit MFMAs
      LOGIT_STORE(A0, B0);
    }
    __syncthreads();
  }

  // ---- epilogue: logits for t=SEQ-1 from final h ----
  if (w == 3) {
    s16x8 aF[KS];
    #pragma unroll
    for (int s = 0; s < KS; ++s) aF[s] = *(const s16x8*)&hA[(s * 64 + lane) * 8];
    f32x4 A0 = zz, B0 = zz;
    MFMA_PAIR(8, A0, B0);
    if (lane < 32) {
      int qrow = (lane >> 4) * 4, c = lane & 15;
      #pragma unroll
      for (int q = 0; q < 4; ++q) {
        int base = (qrow + q) * SV + (SEQ - 1) * VOCAB;
        logL[base + c] = A0[q];
        if (c < 2) logL[base + 16 + c] = B0[q];
      }
    }
  }
  __syncthreads();

  // ---- flush logits: block's region is contiguous [blk*8 rows][128][18] ----
  float* dst = out + (size_t)blk * (MB * SV);
  for (int i = tid * 4; i < MB * SV; i += TPB * 4)
    *(f32x4*)&dst[i] = *(const f32x4*)&logL[i];

#undef MFMA_PAIR
#undef TRANS4
#undef EWONE
#undef EW_PAIR
#undef LOGIT_STORE
}

extern "C" void kernel_launch(void* const* d_in, const int* in_sizes, int n_in,
                              void* d_out, int out_size, void* d_ws, size_t ws_size,
                              hipStream_t stream) {
  const int*   x     = (const int*)  d_in[0];
  const float* E     = (const float*)d_in[1];
  const float* W_ih  = (const float*)d_in[2];
  const float* W_hh  = (const float*)d_in[3];
  const float* b_ih  = (const float*)d_in[4];
  const float* b_hh  = (const float*)d_in[5];
  const float* W_out = (const float*)d_in[6];
  const float* b_out = (const float*)d_in[7];
  float* out = (float*)d_out;

  // ws layout: tbl 18*800*2 = 28800B | Wp 56*7*64*8*2 = 401408B   (~430KB)
  unsigned short* tbl = (unsigned short*)d_ws;
  short* Wp = (short*)d_ws + VOCAB * G4;

  prep_tbl<<<(VOCAB * G4 + 255) / 256, 256, 0, stream>>>(E, W_ih, b_ih, b_hh, tbl);
  prep_wp<<<(NT * KS * 64 + 255) / 256, 256, 0, stream>>>(W_hh, W_out, b_out, tbl, Wp);
  lstm_kernel<<<BATCH / MB, TPB, 0, stream>>>(x, Wp, out);
}